// Round 1
// baseline (577.347 us; speedup 1.0000x reference)
//
#include <hip/hip_runtime.h>
#include <cstdint>
#include <cstddef>

// GAT (2 layers, H=2) + MLP head for MI355X. Round 1: correctness-first fp32.
// Key algebraic optimization: attention logits a_s/a_d computed as x @ V where
// V[k,j] = sum_c W[k, h*C+c]*att[h,c]  -- avoids materializing xd entirely.

// ---------------- fold attention vector into weight matrix ----------------
// V[k*4 + joff + h] = sum_c W[k*(2C) + h*C + c] * att[h*C + c]
__global__ void fold_att(const float* __restrict__ W, const float* __restrict__ att,
                         float* __restrict__ V, int C, int joff) {
  int k = blockIdx.x, h = blockIdx.y, lane = threadIdx.x;
  const float* wr = W + (size_t)k * (2 * C) + (size_t)h * C;
  const float* ar = att + (size_t)h * C;
  float s = 0.f;
  for (int c = lane; c < C; c += 64) s += wr[c] * ar[c];
#pragma unroll
  for (int o = 32; o > 0; o >>= 1) s += __shfl_down(s, o);
  if (lane == 0) V[k * 4 + joff + h] = s;
}

// ---------------- a = X @ V, V is [K,4]; one wave per node ----------------
__global__ __launch_bounds__(256) void compute_a(const float* __restrict__ X,
                                                 const float* __restrict__ V,
                                                 float* __restrict__ A, int N, int K) {
  int node = blockIdx.x * 4 + (threadIdx.x >> 6);
  int lane = threadIdx.x & 63;
  if (node >= N) return;
  const float* xr = X + (size_t)node * K;
  float s0 = 0, s1 = 0, s2 = 0, s3 = 0;
  for (int k = lane; k < K; k += 64) {
    float xv = xr[k];
    float4 v = ((const float4*)V)[k];
    s0 += xv * v.x; s1 += xv * v.y; s2 += xv * v.z; s3 += xv * v.w;
  }
#pragma unroll
  for (int o = 32; o > 0; o >>= 1) {
    s0 += __shfl_down(s0, o); s1 += __shfl_down(s1, o);
    s2 += __shfl_down(s2, o); s3 += __shfl_down(s3, o);
  }
  if (lane == 0) ((float4*)A)[node] = make_float4(s0, s1, s2, s3);
}

// ---------------- CSR build: histogram, scan, scatter ----------------
__global__ void hist_kernel(const int* __restrict__ dst, int* __restrict__ counts, int E) {
  int e = blockIdx.x * 256 + threadIdx.x;
  if (e < E) atomicAdd(&counts[dst[e]], 1);
}

// single block, 1024 threads, 10 elements each (N <= 10240)
__global__ __launch_bounds__(1024) void scan_kernel(const int* __restrict__ counts,
                                                    int* __restrict__ offs,
                                                    int* __restrict__ cursor, int N) {
  __shared__ int part[1024];
  int t = threadIdx.x;
  int base = t * 10;
  int local[10];
  int s = 0;
#pragma unroll
  for (int i = 0; i < 10; i++) {
    int idx = base + i;
    local[i] = s;
    s += (idx < N) ? counts[idx] : 0;
  }
  part[t] = s;
  __syncthreads();
  for (int o = 1; o < 1024; o <<= 1) {
    int v = (t >= o) ? part[t - o] : 0;
    __syncthreads();
    part[t] += v;
    __syncthreads();
  }
  int excl = (t == 0) ? 0 : part[t - 1];
#pragma unroll
  for (int i = 0; i < 10; i++) {
    int idx = base + i;
    if (idx < N) { int o = excl + local[i]; offs[idx] = o; cursor[idx] = o; }
  }
  if (t == 1023) offs[N] = part[1023];
}

__global__ void fill_kernel(const int* __restrict__ srcs, const int* __restrict__ dsts,
                            int* __restrict__ cursor, int* __restrict__ csr, int E) {
  int e = blockIdx.x * 256 + threadIdx.x;
  if (e < E) {
    int d = dsts[e];
    int p = atomicAdd(&cursor[d], 1);
    csr[p] = srcs[e];
  }
}

// ---------------- fp32 tiled GEMM: 64x64 tile, 4x4 per thread ----------------
__global__ __launch_bounds__(256) void gemm_f32(const float* __restrict__ A,
                                                const float* __restrict__ B,
                                                float* __restrict__ C, int M, int N, int K,
                                                const float* __restrict__ bias, int do_relu) {
  __shared__ float As[16][68];  // [k][m], padded for bank-conflict-free transpose store
  __shared__ float Bs[16][68];  // [k][n]
  int tid = threadIdx.x;
  int row0 = blockIdx.y * 64, col0 = blockIdx.x * 64;
  int tx = tid & 15, ty = tid >> 4;
  int arow = tid >> 2, ak = (tid & 3) * 4;
  int bk = tid >> 4, bcol = (tid & 15) * 4;
  float acc[4][4] = {};
  for (int k0 = 0; k0 < K; k0 += 16) {
    float4 av = make_float4(0, 0, 0, 0);
    int grow = row0 + arow;
    if (grow < M) av = *(const float4*)(A + (size_t)grow * K + (k0 + ak));
    As[ak + 0][arow] = av.x; As[ak + 1][arow] = av.y;
    As[ak + 2][arow] = av.z; As[ak + 3][arow] = av.w;
    float4 bv = *(const float4*)(B + (size_t)(k0 + bk) * N + (col0 + bcol));
    *(float4*)&Bs[bk][bcol] = bv;
    __syncthreads();
#pragma unroll
    for (int kk = 0; kk < 16; kk++) {
      float4 a4 = *(const float4*)&As[kk][ty * 4];
      float4 b4 = *(const float4*)&Bs[kk][tx * 4];
      float ar[4] = {a4.x, a4.y, a4.z, a4.w};
      float br[4] = {b4.x, b4.y, b4.z, b4.w};
#pragma unroll
      for (int i = 0; i < 4; i++)
#pragma unroll
        for (int j = 0; j < 4; j++) acc[i][j] += ar[i] * br[j];
    }
    __syncthreads();
  }
#pragma unroll
  for (int i = 0; i < 4; i++) {
    int r = row0 + ty * 4 + i;
    if (r >= M) continue;
    int c = col0 + tx * 4;
    float4 o;
    o.x = acc[i][0]; o.y = acc[i][1]; o.z = acc[i][2]; o.w = acc[i][3];
    if (bias) { o.x += bias[c + 0]; o.y += bias[c + 1]; o.z += bias[c + 2]; o.w += bias[c + 3]; }
    if (do_relu) { o.x = fmaxf(o.x, 0.f); o.y = fmaxf(o.y, 0.f); o.z = fmaxf(o.z, 0.f); o.w = fmaxf(o.w, 0.f); }
    *(float4*)(C + (size_t)r * N + c) = o;
  }
}

// ---------------- per-node softmax-weighted aggregation ----------------
// One block (256 threads) per dst node. CT = J*256 total channels, head 0 = [0,CT/2).
// Self-loop handled implicitly as edge index == deg.
template <int J>
__global__ __launch_bounds__(256) void aggregate(const float* __restrict__ xs,
                                                 const float* __restrict__ a,
                                                 const int* __restrict__ offs,
                                                 const int* __restrict__ csr,
                                                 const float* __restrict__ bias,
                                                 float* __restrict__ out, int N) {
  constexpr int CT = J * 256;
  int v = blockIdx.x;
  int t = threadIdx.x;
  int o0 = offs[v];
  int deg = offs[v + 1] - o0;
  int cnt = deg + 1;  // + self-loop
  float4 av = ((const float4*)a)[v];
  float ad0 = av.z, ad1 = av.w;

  // phase A: segment max per head
  float m0 = -1e30f, m1 = -1e30f;
  for (int i = t; i < cnt; i += 256) {
    int s = (i < deg) ? csr[o0 + i] : v;
    float4 as = ((const float4*)a)[s];
    float e0 = as.x + ad0; e0 = e0 > 0.f ? e0 : 0.2f * e0;
    float e1 = as.y + ad1; e1 = e1 > 0.f ? e1 : 0.2f * e1;
    m0 = fmaxf(m0, e0); m1 = fmaxf(m1, e1);
  }
#pragma unroll
  for (int o = 32; o > 0; o >>= 1) {
    m0 = fmaxf(m0, __shfl_down(m0, o));
    m1 = fmaxf(m1, __shfl_down(m1, o));
  }
  __shared__ float sm[8];
  int w = t >> 6;
  if ((t & 63) == 0) { sm[w * 2 + 0] = m0; sm[w * 2 + 1] = m1; }
  __syncthreads();
  if (t < 2) {
    float mm = -1e30f;
#pragma unroll
    for (int ww = 0; ww < 4; ww++) mm = fmaxf(mm, sm[ww * 2 + t]);
    sm[t] = mm;
  }
  __syncthreads();
  m0 = sm[0]; m1 = sm[1];

  // phase B: accumulate exp(e-m)*xs ; divide by denom at the end
  float acc[J];
#pragma unroll
  for (int j = 0; j < J; j++) acc[j] = 0.f;
  float den0 = 0.f, den1 = 0.f;
  bool head0 = (t < 128);  // channels c = t*J + j ; c < CT/2 <=> t < 128
  for (int i = 0; i < cnt; i++) {
    int s = (i < deg) ? csr[o0 + i] : v;
    float4 as = ((const float4*)a)[s];
    float e0 = as.x + ad0; e0 = e0 > 0.f ? e0 : 0.2f * e0;
    float e1 = as.y + ad1; e1 = e1 > 0.f ? e1 : 0.2f * e1;
    float w0 = __expf(e0 - m0), w1 = __expf(e1 - m1);
    den0 += w0; den1 += w1;
    float wv = head0 ? w0 : w1;
    const float* xr = xs + (size_t)s * CT + t * J;
    if constexpr (J == 4) {
      float4 xv = *(const float4*)xr;
      acc[0] += wv * xv.x; acc[1] += wv * xv.y; acc[2] += wv * xv.z; acc[3] += wv * xv.w;
    } else {
      float2 xv = *(const float2*)xr;
      acc[0] += wv * xv.x; acc[1] += wv * xv.y;
    }
  }
  float den = head0 ? den0 : den1;
  float r[J];
#pragma unroll
  for (int j = 0; j < J; j++) {
    float val = acc[j] / den + bias[t * J + j];
    r[j] = val > 0.f ? val : 0.f;  // relu fused (both layers are relu'd)
  }
  float* orow = out + (size_t)v * CT + t * J;
  if constexpr (J == 4) *(float4*)orow = make_float4(r[0], r[1], r[2], r[3]);
  else *(float2*)orow = make_float2(r[0], r[1]);
}

// ---------------- MLP tail ----------------
__global__ __launch_bounds__(128) void col_stats(const float* __restrict__ z,
                                                 float* __restrict__ sums, int N) {
  int j = threadIdx.x;
  float s = 0.f, s2 = 0.f;
  for (int n = blockIdx.x; n < N; n += gridDim.x) {
    float v = z[(size_t)n * 128 + j];
    s += v; s2 += v * v;
  }
  atomicAdd(&sums[j], s);
  atomicAdd(&sums[128 + j], s2);
}

__global__ void finalize_stats(const float* __restrict__ sums, float* __restrict__ mr, int N) {
  int j = threadIdx.x;  // 128 threads
  float mean = sums[j] / (float)N;
  float var = sums[128 + j] / (float)N - mean * mean;
  mr[j] = mean;
  mr[128 + j] = rsqrtf(var + 1e-5f);
}

__global__ __launch_bounds__(128) void head_kernel(const float* __restrict__ z,
                                                   const float* __restrict__ mr,
                                                   const float* __restrict__ gamma,
                                                   const float* __restrict__ beta,
                                                   const float* __restrict__ wf2,
                                                   const float* __restrict__ bf2,
                                                   float* __restrict__ out, int N) {
  __shared__ float red[3][128];
  int v = blockIdx.x, j = threadIdx.x;
  float h = z[(size_t)v * 128 + j];
  h = gamma[j] * (h - mr[j]) * mr[128 + j] + beta[j];
  h = h > 0.f ? h : 0.f;
  red[0][j] = h * wf2[j * 3 + 0];
  red[1][j] = h * wf2[j * 3 + 1];
  red[2][j] = h * wf2[j * 3 + 2];
  __syncthreads();
  for (int o = 64; o > 0; o >>= 1) {
    if (j < o) {
      red[0][j] += red[0][j + o];
      red[1][j] += red[1][j + o];
      red[2][j] += red[2][j + o];
    }
    __syncthreads();
  }
  if (j == 0) {
    float l0 = red[0][0] + bf2[0], l1 = red[1][0] + bf2[1], l2 = red[2][0] + bf2[2];
    float mx = fmaxf(l0, fmaxf(l1, l2));
    float lse = mx + logf(__expf(l0 - mx) + __expf(l1 - mx) + __expf(l2 - mx));
    out[v * 3 + 0] = l0 - lse;
    out[v * 3 + 1] = l1 - lse;
    out[v * 3 + 2] = l2 - lse;
  }
}

extern "C" void kernel_launch(void* const* d_in, const int* in_sizes, int n_in,
                              void* d_out, int out_size, void* d_ws, size_t ws_size,
                              hipStream_t stream) {
  const float* x     = (const float*)d_in[0];
  const int*   ei    = (const int*)d_in[1];
  const float* w1s   = (const float*)d_in[2];
  const float* w1d   = (const float*)d_in[3];
  const float* a1s   = (const float*)d_in[4];
  const float* a1d   = (const float*)d_in[5];
  const float* b1    = (const float*)d_in[6];
  const float* w2s   = (const float*)d_in[7];
  const float* w2d   = (const float*)d_in[8];
  const float* a2s   = (const float*)d_in[9];
  const float* a2d   = (const float*)d_in[10];
  const float* b2    = (const float*)d_in[11];
  const float* wf1   = (const float*)d_in[12];
  const float* bf1   = (const float*)d_in[13];
  const float* gamma = (const float*)d_in[14];
  const float* beta  = (const float*)d_in[15];
  const float* wf2   = (const float*)d_in[16];
  const float* bf2   = (const float*)d_in[17];
  float* out = (float*)d_out;

  const int N = in_sizes[0] / 256;  // 10000
  const int E = in_sizes[1] / 2;    // 160000
  (void)n_in; (void)out_size; (void)ws_size;

  char* ws = (char*)d_ws;
  size_t off = 0;
  auto alloc = [&](size_t bytes) -> char* {
    off = (off + 255) & ~(size_t)255;
    char* p = ws + off;
    off += bytes;
    return p;
  };
  // slot reuse keeps peak at ~104 MB
  float* slot0 = (float*)alloc((size_t)N * 1024 * 4);  // xs1 (N*512) then h2 (N*1024)
  float* slot1 = (float*)alloc((size_t)N * 512 * 4);   // h1 then z (N*128)
  float* slot2 = (float*)alloc((size_t)N * 1024 * 4);  // xs2
  float* a1    = (float*)alloc((size_t)N * 16);
  float* a2    = (float*)alloc((size_t)N * 16);
  float* V1    = (float*)alloc(256 * 16);
  float* V2    = (float*)alloc(512 * 16);
  int* counts  = (int*)alloc((size_t)N * 4);
  int* offs    = (int*)alloc((size_t)(N + 1) * 4);
  int* cursor  = (int*)alloc((size_t)N * 4);
  int* csr     = (int*)alloc((size_t)E * 4);
  float* sums  = (float*)alloc(256 * 4);
  float* mr    = (float*)alloc(256 * 4);

  float* xs1 = slot0;
  float* h1  = slot1;
  float* xs2 = slot2;
  float* h2  = slot0;  // xs1 dead after aggregate<2>
  float* z   = slot1;  // h1 dead after gemm2 + compute_a(a2)

  hipMemsetAsync(counts, 0, (size_t)N * 4, stream);
  hipMemsetAsync(sums, 0, 256 * 4, stream);

  // fold attention vectors into weights: V[:,0:2]=src part, V[:,2:4]=dst part
  fold_att<<<dim3(256, 2), 64, 0, stream>>>(w1s, a1s, V1, 256, 0);
  fold_att<<<dim3(256, 2), 64, 0, stream>>>(w1d, a1d, V1, 256, 2);
  fold_att<<<dim3(512, 2), 64, 0, stream>>>(w2s, a2s, V2, 512, 0);
  fold_att<<<dim3(512, 2), 64, 0, stream>>>(w2d, a2d, V2, 512, 2);

  // CSR by dst (self-loops handled implicitly in aggregate)
  const int* srcs = ei;
  const int* dsts = ei + E;
  hist_kernel<<<(E + 255) / 256, 256, 0, stream>>>(dsts, counts, E);
  scan_kernel<<<1, 1024, 0, stream>>>(counts, offs, cursor, N);
  fill_kernel<<<(E + 255) / 256, 256, 0, stream>>>(srcs, dsts, cursor, csr, E);

  int mb = (N + 63) / 64;
  // layer 1
  gemm_f32<<<dim3(512 / 64, mb), 256, 0, stream>>>(x, w1s, xs1, N, 512, 256, nullptr, 0);
  compute_a<<<(N + 3) / 4, 256, 0, stream>>>(x, V1, a1, N, 256);
  aggregate<2><<<N, 256, 0, stream>>>(xs1, a1, offs, csr, b1, h1, N);
  // layer 2
  gemm_f32<<<dim3(1024 / 64, mb), 256, 0, stream>>>(h1, w2s, xs2, N, 1024, 512, nullptr, 0);
  compute_a<<<(N + 3) / 4, 256, 0, stream>>>(h1, V2, a2, N, 512);
  aggregate<4><<<N, 256, 0, stream>>>(xs2, a2, offs, csr, b2, h2, N);
  // MLP head
  gemm_f32<<<dim3(128 / 64, mb), 256, 0, stream>>>(h2, wf1, z, N, 128, 1024, bf1, 0);
  col_stats<<<120, 128, 0, stream>>>(z, sums, N);
  finalize_stats<<<1, 128, 0, stream>>>(sums, mr, N);
  head_kernel<<<N, 128, 0, stream>>>(z, mr, gamma, beta, wf2, bf2, out, N);
}

// Round 2
// 363.118 us; speedup vs baseline: 1.5900x; 1.5900x over previous
//
#include <hip/hip_runtime.h>
#include <cstdint>
#include <cstddef>

// GAT (2 layers, H=2) + MLP head for MI355X. Round 2: bf16 MFMA GEMMs.
// - attention logits folded into x @ V (no xd materialization)
// - weights pre-transposed to [N][K] bf16 so A and B fragments are both
//   contiguous-in-K ds_read_b128
// - global_load_lds width=16 staging, 128x128 tile, 16x16x32 bf16 MFMA
// - activations stored bf16 (halves aggregate gather traffic)
// - bf1 bias dropped: cancels exactly through column-wise LayerNorm

typedef unsigned short u16;
typedef __bf16 bf16x8 __attribute__((ext_vector_type(8)));
typedef float f32x4 __attribute__((ext_vector_type(4)));

__device__ __forceinline__ u16 f2b(float f) {
  union { float f; uint32_t u; } c; c.f = f;
  uint32_t u = c.u;
  return (u16)((u + 0x7FFFu + ((u >> 16) & 1u)) >> 16);
}
__device__ __forceinline__ float b2f(u16 h) {
  union { uint32_t u; float f; } c; c.u = ((uint32_t)h) << 16;
  return c.f;
}

__device__ __forceinline__ void async16(const void* g, void* l) {
  __builtin_amdgcn_global_load_lds((const __attribute__((address_space(1))) void*)g,
                                   (__attribute__((address_space(3))) void*)l, 16, 0, 0);
}

// ---------------- conversions ----------------
__global__ void cvt_x(const float* __restrict__ X, u16* __restrict__ out, int M, int total, int K) {
  int idx = blockIdx.x * 256 + threadIdx.x;
  if (idx >= total) return;
  int r = idx / K;
  out[idx] = f2b(r < M ? X[idx] : 0.f);
}

// W [K][Ncols] fp32 -> out [Ncols][K] bf16 (transposed)
__global__ void cvt_wT(const float* __restrict__ W, u16* __restrict__ out, int K, int Ncols) {
  int idx = blockIdx.x * 256 + threadIdx.x;
  if (idx >= K * Ncols) return;
  int k = idx / Ncols, n = idx - k * Ncols;
  out[n * K + k] = f2b(W[idx]);
}

// ---------------- fold attention vector into weight matrix ----------------
__global__ void fold_att(const float* __restrict__ W, const float* __restrict__ att,
                         float* __restrict__ V, int C, int joff) {
  int k = blockIdx.x, h = blockIdx.y, lane = threadIdx.x;
  const float* wr = W + (size_t)k * (2 * C) + (size_t)h * C;
  const float* ar = att + (size_t)h * C;
  float s = 0.f;
  for (int c = lane; c < C; c += 64) s += wr[c] * ar[c];
#pragma unroll
  for (int o = 32; o > 0; o >>= 1) s += __shfl_down(s, o);
  if (lane == 0) V[k * 4 + joff + h] = s;
}

// ---------------- a = X @ V (fp32 X) ----------------
__global__ __launch_bounds__(256) void compute_a(const float* __restrict__ X,
                                                 const float* __restrict__ V,
                                                 float* __restrict__ A, int N, int K) {
  int node = blockIdx.x * 4 + (threadIdx.x >> 6);
  int lane = threadIdx.x & 63;
  if (node >= N) return;
  const float* xr = X + (size_t)node * K;
  float s0 = 0, s1 = 0, s2 = 0, s3 = 0;
  for (int k = lane; k < K; k += 64) {
    float xv = xr[k];
    float4 v = ((const float4*)V)[k];
    s0 += xv * v.x; s1 += xv * v.y; s2 += xv * v.z; s3 += xv * v.w;
  }
#pragma unroll
  for (int o = 32; o > 0; o >>= 1) {
    s0 += __shfl_down(s0, o); s1 += __shfl_down(s1, o);
    s2 += __shfl_down(s2, o); s3 += __shfl_down(s3, o);
  }
  if (lane == 0) ((float4*)A)[node] = make_float4(s0, s1, s2, s3);
}

// ---------------- a = X @ V (bf16 X) ----------------
__global__ __launch_bounds__(256) void compute_a_b16(const u16* __restrict__ X,
                                                     const float* __restrict__ V,
                                                     float* __restrict__ A, int N, int K) {
  int node = blockIdx.x * 4 + (threadIdx.x >> 6);
  int lane = threadIdx.x & 63;
  if (node >= N) return;
  const u16* xr = X + (size_t)node * K;
  float s0 = 0, s1 = 0, s2 = 0, s3 = 0;
  for (int k = lane; k < K; k += 64) {
    float xv = b2f(xr[k]);
    float4 v = ((const float4*)V)[k];
    s0 += xv * v.x; s1 += xv * v.y; s2 += xv * v.z; s3 += xv * v.w;
  }
#pragma unroll
  for (int o = 32; o > 0; o >>= 1) {
    s0 += __shfl_down(s0, o); s1 += __shfl_down(s1, o);
    s2 += __shfl_down(s2, o); s3 += __shfl_down(s3, o);
  }
  if (lane == 0) ((float4*)A)[node] = make_float4(s0, s1, s2, s3);
}

// ---------------- CSR build ----------------
__global__ void hist_kernel(const int* __restrict__ dst, int* __restrict__ counts, int E) {
  int e = blockIdx.x * 256 + threadIdx.x;
  if (e < E) atomicAdd(&counts[dst[e]], 1);
}

__global__ __launch_bounds__(1024) void scan_kernel(const int* __restrict__ counts,
                                                    int* __restrict__ offs,
                                                    int* __restrict__ cursor, int N) {
  __shared__ int part[1024];
  int t = threadIdx.x;
  int base = t * 10;
  int local[10];
  int s = 0;
#pragma unroll
  for (int i = 0; i < 10; i++) {
    int idx = base + i;
    local[i] = s;
    s += (idx < N) ? counts[idx] : 0;
  }
  part[t] = s;
  __syncthreads();
  for (int o = 1; o < 1024; o <<= 1) {
    int v = (t >= o) ? part[t - o] : 0;
    __syncthreads();
    part[t] += v;
    __syncthreads();
  }
  int excl = (t == 0) ? 0 : part[t - 1];
#pragma unroll
  for (int i = 0; i < 10; i++) {
    int idx = base + i;
    if (idx < N) { int o = excl + local[i]; offs[idx] = o; cursor[idx] = o; }
  }
  if (t == 1023) offs[N] = part[1023];
}

__global__ void fill_kernel(const int* __restrict__ srcs, const int* __restrict__ dsts,
                            int* __restrict__ cursor, int* __restrict__ csr, int E) {
  int e = blockIdx.x * 256 + threadIdx.x;
  if (e < E) {
    int d = dsts[e];
    int p = atomicAdd(&cursor[d], 1);
    csr[p] = srcs[e];
  }
}

// ---------------- bf16 MFMA GEMM: C[M][N] = A[M][K] * BT[N][K]^T ----------------
// 128x128 tile, BK=32, 4 waves in 2x2, each wave 64x64 via 4x4 16x16x32 frags.
// Mpad rows (multiple of 128); N multiple of 128; K multiple of 32.
// If gridDim.z>1: split-K, block z handles K-range [z*Ksplit, (z+1)*Ksplit),
// output written to slab z (C + z*slabStride).
template <bool OUT_BF16>
__global__ __launch_bounds__(256) void gemm_bf16(const u16* __restrict__ A,
                                                 const u16* __restrict__ BT,
                                                 void* __restrict__ Cv,
                                                 int N, int K, int Ksplit,
                                                 size_t slabStride) {
  __shared__ u16 Asl[128 * 32];
  __shared__ u16 Bsl[128 * 32];
  int tid = threadIdx.x;
  int wave = tid >> 6, lane = tid & 63;
  int wr = wave >> 1, wc = wave & 1;
  int lr = lane & 15, quad = lane >> 4;
  size_t row0 = (size_t)blockIdx.y * 128;
  size_t n0 = (size_t)blockIdx.x * 128;
  int k0base = blockIdx.z * Ksplit;

  f32x4 acc[4][4];
#pragma unroll
  for (int i = 0; i < 4; i++)
#pragma unroll
    for (int j = 0; j < 4; j++) acc[i][j] = (f32x4){0.f, 0.f, 0.f, 0.f};

  int ra = tid >> 2;          // 0..63
  int ca = (tid & 3) * 8;     // 0,8,16,24
  const u16* gA = A + (row0 + ra) * K + ca;
  const u16* gB = BT + (n0 + ra) * K + ca;
  u16* lA = &Asl[(tid & 192) * 8];  // wave-uniform: wave*512 elements
  u16* lB = &Bsl[(tid & 192) * 8];

  for (int k0 = k0base; k0 < k0base + Ksplit; k0 += 32) {
    async16(gA + k0, lA);
    async16(gA + (size_t)64 * K + k0, lA + 2048);
    async16(gB + k0, lB);
    async16(gB + (size_t)64 * K + k0, lB + 2048);
    __syncthreads();
    bf16x8 av[4], bv[4];
#pragma unroll
    for (int i = 0; i < 4; i++)
      av[i] = *(const bf16x8*)&Asl[(wr * 64 + i * 16 + lr) * 32 + quad * 8];
#pragma unroll
    for (int j = 0; j < 4; j++)
      bv[j] = *(const bf16x8*)&Bsl[(wc * 64 + j * 16 + lr) * 32 + quad * 8];
#pragma unroll
    for (int i = 0; i < 4; i++)
#pragma unroll
      for (int j = 0; j < 4; j++)
        acc[i][j] = __builtin_amdgcn_mfma_f32_16x16x32_bf16(av[i], bv[j], acc[i][j], 0, 0, 0);
    __syncthreads();
  }

  size_t crow = row0 + wr * 64 + quad * 4;
  size_t ccol = n0 + wc * 64 + lr;
  if (OUT_BF16) {
    u16* C = (u16*)Cv;
#pragma unroll
    for (int i = 0; i < 4; i++)
#pragma unroll
      for (int j = 0; j < 4; j++)
#pragma unroll
        for (int r = 0; r < 4; r++)
          C[(crow + i * 16 + r) * N + ccol + j * 16] = f2b(acc[i][j][r]);
  } else {
    float* C = (float*)Cv + (size_t)blockIdx.z * slabStride;
#pragma unroll
    for (int i = 0; i < 4; i++)
#pragma unroll
      for (int j = 0; j < 4; j++)
#pragma unroll
        for (int r = 0; r < 4; r++)
          C[(crow + i * 16 + r) * N + ccol + j * 16] = acc[i][j][r];
  }
}

// ---------------- per-node softmax-weighted aggregation (bf16 in/out) ----------------
template <int J>
__global__ __launch_bounds__(256) void aggregate(const u16* __restrict__ xs,
                                                 const float* __restrict__ a,
                                                 const int* __restrict__ offs,
                                                 const int* __restrict__ csr,
                                                 const float* __restrict__ bias,
                                                 u16* __restrict__ out, int N) {
  constexpr int CT = J * 256;
  int v = blockIdx.x;
  int t = threadIdx.x;
  int o0 = offs[v];
  int deg = offs[v + 1] - o0;
  int cnt = deg + 1;  // + self-loop
  float4 av = ((const float4*)a)[v];
  float ad0 = av.z, ad1 = av.w;

  // phase A: segment max per head
  float m0 = -1e30f, m1 = -1e30f;
  for (int i = t; i < cnt; i += 256) {
    int s = (i < deg) ? csr[o0 + i] : v;
    float4 as = ((const float4*)a)[s];
    float e0 = as.x + ad0; e0 = e0 > 0.f ? e0 : 0.2f * e0;
    float e1 = as.y + ad1; e1 = e1 > 0.f ? e1 : 0.2f * e1;
    m0 = fmaxf(m0, e0); m1 = fmaxf(m1, e1);
  }
#pragma unroll
  for (int o = 32; o > 0; o >>= 1) {
    m0 = fmaxf(m0, __shfl_down(m0, o));
    m1 = fmaxf(m1, __shfl_down(m1, o));
  }
  __shared__ float sm[8];
  int w = t >> 6;
  if ((t & 63) == 0) { sm[w * 2 + 0] = m0; sm[w * 2 + 1] = m1; }
  __syncthreads();
  if (t < 2) {
    float mm = -1e30f;
#pragma unroll
    for (int ww = 0; ww < 4; ww++) mm = fmaxf(mm, sm[ww * 2 + t]);
    sm[t] = mm;
  }
  __syncthreads();
  m0 = sm[0]; m1 = sm[1];

  // phase B
  float acc[J];
#pragma unroll
  for (int j = 0; j < J; j++) acc[j] = 0.f;
  float den0 = 0.f, den1 = 0.f;
  bool head0 = (t < 128);
  for (int i = 0; i < cnt; i++) {
    int s = (i < deg) ? csr[o0 + i] : v;
    float4 as = ((const float4*)a)[s];
    float e0 = as.x + ad0; e0 = e0 > 0.f ? e0 : 0.2f * e0;
    float e1 = as.y + ad1; e1 = e1 > 0.f ? e1 : 0.2f * e1;
    float w0 = __expf(e0 - m0), w1 = __expf(e1 - m1);
    den0 += w0; den1 += w1;
    float wv = head0 ? w0 : w1;
    const u16* xr = xs + (size_t)s * CT + t * J;
    if constexpr (J == 4) {
      ushort4 xv = *(const ushort4*)xr;
      acc[0] += wv * b2f(xv.x); acc[1] += wv * b2f(xv.y);
      acc[2] += wv * b2f(xv.z); acc[3] += wv * b2f(xv.w);
    } else {
      ushort2 xv = *(const ushort2*)xr;
      acc[0] += wv * b2f(xv.x); acc[1] += wv * b2f(xv.y);
    }
  }
  float den = head0 ? den0 : den1;
  u16 r[J];
#pragma unroll
  for (int j = 0; j < J; j++) {
    float val = acc[j] / den + bias[t * J + j];
    r[j] = f2b(val > 0.f ? val : 0.f);
  }
  u16* orow = out + (size_t)v * CT + t * J;
  if constexpr (J == 4) *(ushort4*)orow = make_ushort4(r[0], r[1], r[2], r[3]);
  else *(ushort2*)orow = make_ushort2(r[0], r[1]);
}

// ---------------- MLP tail (z in 4 split-K slabs) ----------------
__global__ __launch_bounds__(128) void col_stats(const float* __restrict__ z, size_t slab,
                                                 float* __restrict__ sums, int N) {
  int j = threadIdx.x;
  float s = 0.f, s2 = 0.f;
  for (int n = blockIdx.x; n < N; n += gridDim.x) {
    const float* p = z + (size_t)n * 128 + j;
    float v = p[0] + p[slab] + p[2 * slab] + p[3 * slab];
    s += v; s2 += v * v;
  }
  atomicAdd(&sums[j], s);
  atomicAdd(&sums[128 + j], s2);
}

__global__ void finalize_stats(const float* __restrict__ sums, float* __restrict__ mr, int N) {
  int j = threadIdx.x;  // 128 threads
  float mean = sums[j] / (float)N;
  float var = sums[128 + j] / (float)N - mean * mean;
  mr[j] = mean;
  mr[128 + j] = rsqrtf(var + 1e-5f);
}

__global__ __launch_bounds__(128) void head_kernel(const float* __restrict__ z, size_t slab,
                                                   const float* __restrict__ mr,
                                                   const float* __restrict__ gamma,
                                                   const float* __restrict__ beta,
                                                   const float* __restrict__ wf2,
                                                   const float* __restrict__ bf2,
                                                   float* __restrict__ out, int N) {
  __shared__ float red[3][128];
  int v = blockIdx.x, j = threadIdx.x;
  const float* p = z + (size_t)v * 128 + j;
  float h = p[0] + p[slab] + p[2 * slab] + p[3 * slab];
  h = gamma[j] * (h - mr[j]) * mr[128 + j] + beta[j];
  h = h > 0.f ? h : 0.f;
  red[0][j] = h * wf2[j * 3 + 0];
  red[1][j] = h * wf2[j * 3 + 1];
  red[2][j] = h * wf2[j * 3 + 2];
  __syncthreads();
  for (int o = 64; o > 0; o >>= 1) {
    if (j < o) {
      red[0][j] += red[0][j + o];
      red[1][j] += red[1][j + o];
      red[2][j] += red[2][j + o];
    }
    __syncthreads();
  }
  if (j == 0) {
    float l0 = red[0][0] + bf2[0], l1 = red[1][0] + bf2[1], l2 = red[2][0] + bf2[2];
    float mx = fmaxf(l0, fmaxf(l1, l2));
    float lse = mx + logf(__expf(l0 - mx) + __expf(l1 - mx) + __expf(l2 - mx));
    out[v * 3 + 0] = l0 - lse;
    out[v * 3 + 1] = l1 - lse;
    out[v * 3 + 2] = l2 - lse;
  }
}

extern "C" void kernel_launch(void* const* d_in, const int* in_sizes, int n_in,
                              void* d_out, int out_size, void* d_ws, size_t ws_size,
                              hipStream_t stream) {
  const float* x     = (const float*)d_in[0];
  const int*   ei    = (const int*)d_in[1];
  const float* w1s   = (const float*)d_in[2];
  const float* a1s   = (const float*)d_in[4];
  const float* a1d   = (const float*)d_in[5];
  const float* b1    = (const float*)d_in[6];
  const float* w2s   = (const float*)d_in[7];
  const float* a2s   = (const float*)d_in[9];
  const float* a2d   = (const float*)d_in[10];
  const float* b2    = (const float*)d_in[11];
  const float* wf1   = (const float*)d_in[12];
  const float* gamma = (const float*)d_in[14];
  const float* beta  = (const float*)d_in[15];
  const float* wf2   = (const float*)d_in[16];
  const float* bf2   = (const float*)d_in[17];
  const float* w1d   = (const float*)d_in[3];
  const float* w2d   = (const float*)d_in[8];
  float* out = (float*)d_out;

  const int N = in_sizes[0] / 256;  // 10000
  const int E = in_sizes[1] / 2;    // 160000
  const int Mpad = ((N + 127) / 128) * 128;  // 10112
  (void)n_in; (void)out_size; (void)ws_size;

  char* ws = (char*)d_ws;
  size_t off = 0;
  auto alloc = [&](size_t bytes) -> char* {
    off = (off + 255) & ~(size_t)255;
    char* p = ws + off;
    off += bytes;
    return p;
  };
  u16* xb    = (u16*)alloc((size_t)Mpad * 256 * 2);
  u16* w1sb  = (u16*)alloc((size_t)512 * 256 * 2);    // [N=512][K=256]
  u16* w2sb  = (u16*)alloc((size_t)1024 * 512 * 2);   // [N=1024][K=512]
  u16* wf1b  = (u16*)alloc((size_t)128 * 1024 * 2);   // [N=128][K=1024]
  u16* xs1   = (u16*)alloc((size_t)Mpad * 512 * 2);
  u16* h1    = (u16*)alloc((size_t)Mpad * 512 * 2);
  u16* xs2   = (u16*)alloc((size_t)Mpad * 1024 * 2);
  u16* h2    = (u16*)alloc((size_t)Mpad * 1024 * 2);
  float* z   = (float*)alloc((size_t)4 * Mpad * 128 * 4);  // 4 split-K slabs
  float* a1  = (float*)alloc((size_t)N * 16);
  float* a2  = (float*)alloc((size_t)N * 16);
  float* V1  = (float*)alloc(256 * 16);
  float* V2  = (float*)alloc(512 * 16);
  int* counts = (int*)alloc((size_t)N * 4);
  int* offs   = (int*)alloc((size_t)(N + 1) * 4);
  int* cursor = (int*)alloc((size_t)N * 4);
  int* csr    = (int*)alloc((size_t)E * 4);
  float* sums = (float*)alloc(256 * 4);
  float* mr   = (float*)alloc(256 * 4);

  hipMemsetAsync(counts, 0, (size_t)N * 4, stream);
  hipMemsetAsync(sums, 0, 256 * 4, stream);
  // zero pad rows of h1/h2 (GEMM A-operand reads them)
  hipMemsetAsync(h1 + (size_t)N * 512, 0, (size_t)(Mpad - N) * 512 * 2, stream);
  hipMemsetAsync(h2 + (size_t)N * 1024, 0, (size_t)(Mpad - N) * 1024 * 2, stream);

  // conversions
  cvt_x<<<(Mpad * 256 + 255) / 256, 256, 0, stream>>>(x, xb, N, Mpad * 256, 256);
  cvt_wT<<<(256 * 512 + 255) / 256, 256, 0, stream>>>(w1s, w1sb, 256, 512);
  cvt_wT<<<(512 * 1024 + 255) / 256, 256, 0, stream>>>(w2s, w2sb, 512, 1024);
  cvt_wT<<<(1024 * 128 + 255) / 256, 256, 0, stream>>>(wf1, wf1b, 1024, 128);

  // fold attention vectors: V[:,0:2]=src part, V[:,2:4]=dst part
  fold_att<<<dim3(256, 2), 64, 0, stream>>>(w1s, a1s, V1, 256, 0);
  fold_att<<<dim3(256, 2), 64, 0, stream>>>(w1d, a1d, V1, 256, 2);
  fold_att<<<dim3(512, 2), 64, 0, stream>>>(w2s, a2s, V2, 512, 0);
  fold_att<<<dim3(512, 2), 64, 0, stream>>>(w2d, a2d, V2, 512, 2);

  // CSR by dst
  const int* srcs = ei;
  const int* dsts = ei + E;
  hist_kernel<<<(E + 255) / 256, 256, 0, stream>>>(dsts, counts, E);
  scan_kernel<<<1, 1024, 0, stream>>>(counts, offs, cursor, N);
  fill_kernel<<<(E + 255) / 256, 256, 0, stream>>>(srcs, dsts, cursor, csr, E);

  int mt = Mpad / 128;  // 79
  // layer 1
  gemm_bf16<true><<<dim3(512 / 128, mt, 1), 256, 0, stream>>>(xb, w1sb, xs1, 512, 256, 256, 0);
  compute_a<<<(N + 3) / 4, 256, 0, stream>>>(x, V1, a1, N, 256);
  aggregate<2><<<N, 256, 0, stream>>>(xs1, a1, offs, csr, b1, h1, N);
  // layer 2
  gemm_bf16<true><<<dim3(1024 / 128, mt, 1), 256, 0, stream>>>(h1, w2sb, xs2, 1024, 512, 512, 0);
  compute_a_b16<<<(N + 3) / 4, 256, 0, stream>>>(h1, V2, a2, N, 512);
  aggregate<4><<<N, 256, 0, stream>>>(xs2, a2, offs, csr, b2, h2, N);
  // MLP head: split-K=4 into 4 slabs (bf1 dropped: cancels in LayerNorm)
  size_t slab = (size_t)Mpad * 128;
  gemm_bf16<false><<<dim3(1, mt, 4), 256, 0, stream>>>(h2, wf1b, z, 128, 1024, 256, slab);
  col_stats<<<120, 128, 0, stream>>>(z, slab, sums, N);
  finalize_stats<<<1, 128, 0, stream>>>(sums, mr, N);
  head_kernel<<<N, 128, 0, stream>>>(z, slab, mr, gamma, beta, wf2, bf2, out, N);
}